// Round 8
// baseline (125.423 us; speedup 1.0000x reference)
//
#include <hip/hip_runtime.h>
#include <hip/hip_bf16.h>
#include <stdint.h>

// pooled[b,i,:] = bias + sum_{j!=i} W_cell(b,i,j) . hid[b,j,:]
// R8: reuse + TLP. grid = 1024 blocks (b 64 x cq 4 x hoq 4) of 4 waves (256thr).
// Wave w owns cells [cq*16+w*4, +4) x ho [hoq*32, +32) x all j — independent
// (R6/R7-verified inner loop): stage-1 32 MFMA (A=hid frags from shared LDS Hs,
// B=W frags from L2-resident Wb), z -> wave-private zscr (XOR swizzle),
// transpose-read, stage-2 16 mask-MFMA (mask from cellt bytes, L2).
// No barriers in the cell loop. End: 4-way intra-block LDS reduction (reusing
// Hs+zscr space) -> partial[cq] (8MB) -> gp_reduce.

typedef __attribute__((ext_vector_type(8))) short bf16x8;
typedef __attribute__((ext_vector_type(4))) float f32x4;
typedef unsigned int u32;

#define NCHUNK 4   // partial chunks (cq)
#define CPW 4      // cells per wave

__device__ inline unsigned short bf16bits(float x) {
    __hip_bfloat16 h = __float2bfloat16(x);
    return *reinterpret_cast<unsigned short*>(&h);
}

// ---- prep: 320 blocks x 256 thr ----
//  blocks [0,256):   wconv  (c = bid>>2, ho-quarter q = bid&3) -> Wb [c][hg][ho][e]
//  blocks [256,320): cell table for b = bid-256
__global__ __launch_bounds__(256)
void gp_prep(const float* __restrict__ W, const float* __restrict__ pos,
             __hip_bfloat16* __restrict__ Wb,      // [64][16][128][8]
             unsigned char* __restrict__ cellt_g)  // [64][64][64]
{
    const int bid = blockIdx.x, t = threadIdx.x;
    if (bid < 256) {
        __shared__ __attribute__((aligned(16))) __hip_bfloat16 Wl[32][136];
        const int c = bid >> 2, q = bid & 3;
        #pragma unroll
        for (int it = 0; it < 4; ++it) {
            int idx = it * 256 + t;           // 1024 float4s
            int r = idx >> 5, k4 = idx & 31;
            float4 v = *(const float4*)(W + (size_t)(q * 32 + r) * 8192 + c * 128 + k4 * 4);
            __hip_bfloat16* d = &Wl[r][k4 * 4];
            d[0] = __float2bfloat16(v.x); d[1] = __float2bfloat16(v.y);
            d[2] = __float2bfloat16(v.z); d[3] = __float2bfloat16(v.w);
        }
        __syncthreads();
        #pragma unroll
        for (int it = 0; it < 2; ++it) {
            int idx = it * 256 + t;           // 512: hg(16) x hol(32)
            int hg = idx >> 5, hol = idx & 31;
            bf16x8 v = *(const bf16x8*)&Wl[hol][hg * 8];
            *(bf16x8*)(Wb + (size_t)c * 16384 + hg * 1024 + (q * 32 + hol) * 8) = v;
        }
    } else {
        __shared__ float ps[128];
        const int b = bid - 256;
        if (t < 128) ps[t] = pos[(size_t)b * 128 + t];
        __syncthreads();
        #pragma unroll
        for (int qq = 0; qq < 16; ++qq) {
            int idx = qq * 256 + t;           // 4096: i x j
            int i = idx >> 6, j = idx & 63;
            float rx = ps[j * 2 + 0] - ps[i * 2 + 0];
            float ry = ps[j * 2 + 1] - ps[i * 2 + 1];
            int gx = (int)((rx + 2.0f) * 2.0f);
            int gy = (int)((ry + 2.0f) * 2.0f);
            gx = gx < 0 ? 0 : (gx > 7 ? 7 : gx);
            gy = gy < 0 ? 0 : (gy > 7 ? 7 : gy);
            cellt_g[(size_t)b * 4096 + idx] =
                (i == j) ? 255 : (unsigned char)(gx * 8 + gy);
        }
    }
}

// ---- main: grid = 1024 blocks (b x cq x hoq), 256 thr (4 waves) ----
__global__ __launch_bounds__(256, 4)
void gp_main(const float* __restrict__ hid,
             const unsigned char* __restrict__ cellt_g,
             const __hip_bfloat16* __restrict__ Wb,
             float* __restrict__ partial)
{
    // carve 32KB: Hs 16KB [hg][j][e] + zscr 4x4KB; reused as red[8192] f32 at end
    __shared__ __attribute__((aligned(16))) char smem[32768];
    __hip_bfloat16* Hs = (__hip_bfloat16*)smem;
    u32* zscr = (u32*)(smem + 16384);
    float* red = (float*)smem;

    const int x = blockIdx.x;
    const int hoq = x & 3, b = (x >> 2) & 63, cq = x >> 8;
    const int t = threadIdx.x;
    const int w = t >> 6, lane = t & 63;
    const int l15 = lane & 15, kg = lane >> 4;

    // stage hid[b] -> Hs [hg][j][e] (f32 -> bf16)  [R6-verified]
    #pragma unroll
    for (int q = 0; q < 4; ++q) {
        int idx = q * 256 + t;
        int hg = idx >> 6, j = idx & 63;
        const float* src = hid + ((size_t)b * 64 + j) * 128 + hg * 8;
        float4 v0 = *(const float4*)src;
        float4 v1 = *(const float4*)(src + 4);
        __hip_bfloat16* d = &Hs[(hg * 64 + j) * 8];
        d[0] = __float2bfloat16(v0.x); d[1] = __float2bfloat16(v0.y);
        d[2] = __float2bfloat16(v0.z); d[3] = __float2bfloat16(v0.w);
        d[4] = __float2bfloat16(v1.x); d[5] = __float2bfloat16(v1.y);
        d[6] = __float2bfloat16(v1.z); d[7] = __float2bfloat16(v1.w);
    }
    __syncthreads();   // barrier 1: Hs ready; waves independent until barrier 2

    u32* zw = zscr + w * 1024;

    f32x4 acc[4][2];
    #pragma unroll
    for (int mt = 0; mt < 4; ++mt) {
        acc[mt][0] = (f32x4){0.f, 0.f, 0.f, 0.f};
        acc[mt][1] = (f32x4){0.f, 0.f, 0.f, 0.f};
    }

    #pragma unroll 1
    for (int cc = 0; cc < CPW; ++cc) {
        const int c = cq * 16 + w * 4 + cc;

        // W B-frags from L2-resident Wb: col ho = hoq*32+fh*16+l15, k=(ks*4+kg)*8..
        bf16x8 wf[4][2];
        #pragma unroll
        for (int ks = 0; ks < 4; ++ks)
            #pragma unroll
            for (int fh = 0; fh < 2; ++fh)
                wf[ks][fh] = *(const bf16x8*)(Wb + (size_t)c * 16384 +
                    ((ks * 4 + kg) * 128 + hoq * 32 + fh * 16 + l15) * 8);

        // stage-1: z[jt][fh] = hid(j x h) @ W_c^T(h x ho), 32 MFMA; A-frags from Hs
        f32x4 z[4][2];
        #pragma unroll
        for (int jt = 0; jt < 4; ++jt) {
            z[jt][0] = (f32x4){0.f, 0.f, 0.f, 0.f};
            z[jt][1] = (f32x4){0.f, 0.f, 0.f, 0.f};
        }
        #pragma unroll
        for (int ks = 0; ks < 4; ++ks) {
            int hg = ks * 4 + kg;
            #pragma unroll
            for (int jt = 0; jt < 4; ++jt) {
                bf16x8 a = *(const bf16x8*)&Hs[(hg * 64 + jt * 16 + l15) * 8];
                z[jt][0] = __builtin_amdgcn_mfma_f32_16x16x32_bf16(a, wf[ks][0], z[jt][0], 0, 0, 0);
                z[jt][1] = __builtin_amdgcn_mfma_f32_16x16x32_bf16(a, wf[ks][1], z[jt][1], 0, 0, 0);
            }
        }

        // pack z -> zw (u32 = bf16 pair (j even, j odd)); D: col=l15=ho, row j
        // jp = j/2; addr32 = (jp*32 + hol) ^ (((jp>>2)&3)<<3)   [R6/R7-verified]
        #pragma unroll
        for (int jt = 0; jt < 4; ++jt)
            #pragma unroll
            for (int fh = 0; fh < 2; ++fh) {
                u32 p0 = (u32)bf16bits(z[jt][fh][0]) | ((u32)bf16bits(z[jt][fh][1]) << 16);
                u32 p1 = (u32)bf16bits(z[jt][fh][2]) | ((u32)bf16bits(z[jt][fh][3]) << 16);
                int X = ((jt * 2 + (kg >> 1)) & 3) << 3;
                int a32 = (((jt * 8 + kg * 2) * 32) + fh * 16 + l15) ^ X;
                zw[a32] = p0;
                zw[a32 + 32] = p1;
            }

        // transpose read: b2[ks2][fh], k=j=ks2*32+kg*8+e   [R6/R7-verified]
        bf16x8 b2[2][2];
        #pragma unroll
        for (int ks2 = 0; ks2 < 2; ++ks2)
            #pragma unroll
            for (int fh = 0; fh < 2; ++fh) {
                int base = (((ks2 * 16 + kg * 4) * 32) + fh * 16 + l15) ^ (kg << 3);
                union { u32 wd[4]; bf16x8 v; } r;
                r.wd[0] = zw[base];
                r.wd[1] = zw[base + 32];
                r.wd[2] = zw[base + 64];
                r.wd[3] = zw[base + 96];
                b2[ks2][fh] = r.v;
            }

        // stage-2: acc(i,ho) += mask(i x j) @ z(j x ho); cellt bytes from L2
        #pragma unroll
        for (int mt = 0; mt < 4; ++mt) {
            #pragma unroll
            for (int ks2 = 0; ks2 < 2; ++ks2) {
                uint2 csv = *(const uint2*)(cellt_g + (size_t)b * 4096 +
                                            (mt * 16 + l15) * 64 + ks2 * 32 + kg * 8);
                union { u32 wd[4]; bf16x8 v; } m;
                #pragma unroll
                for (int k = 0; k < 4; ++k) {
                    u32 s = (k < 2) ? csv.x : csv.y;
                    u32 b0 = (s >> ((k & 1) * 16)) & 0xFFu;
                    u32 b1 = (s >> ((k & 1) * 16 + 8)) & 0xFFu;
                    m.wd[k] = (b0 == (u32)c ? 0x3F80u : 0u) | (b1 == (u32)c ? 0x3F800000u : 0u);
                }
                acc[mt][0] = __builtin_amdgcn_mfma_f32_16x16x32_bf16(m.v, b2[ks2][0], acc[mt][0], 0, 0, 0);
                acc[mt][1] = __builtin_amdgcn_mfma_f32_16x16x32_bf16(m.v, b2[ks2][1], acc[mt][1], 0, 0, 0);
            }
        }
    }

    __syncthreads();   // barrier 2: all waves done with Hs/zscr; safe to overwrite

    // write per-wave acc into red[w][i][hol]  (i = mt*16+kg*4+r, hol = fh*16+l15)
    #pragma unroll
    for (int mt = 0; mt < 4; ++mt)
        #pragma unroll
        for (int fh = 0; fh < 2; ++fh)
            #pragma unroll
            for (int r = 0; r < 4; ++r)
                red[w * 2048 + (mt * 16 + kg * 4 + r) * 32 + fh * 16 + l15] = acc[mt][fh][r];

    __syncthreads();   // barrier 3: red complete

    // 4-way sum + write partial[cq][b][i][hoq*32..]
    #pragma unroll
    for (int rep = 0; rep < 2; ++rep) {
        int e = t * 8 + rep * 4;             // 0..2047, float4-aligned
        float4 s0 = *(const float4*)&red[e];
        float4 s1 = *(const float4*)&red[2048 + e];
        float4 s2 = *(const float4*)&red[4096 + e];
        float4 s3 = *(const float4*)&red[6144 + e];
        float4 s = make_float4(s0.x + s1.x + s2.x + s3.x,
                               s0.y + s1.y + s2.y + s3.y,
                               s0.z + s1.z + s2.z + s3.z,
                               s0.w + s1.w + s2.w + s3.w);
        int i = e >> 5, hol = e & 31;
        *(float4*)(partial + (((size_t)cq * 64 + b) * 64 + i) * 128 + hoq * 32 + hol) = s;
    }
}

// ---- reduce: out = bias + sum_chunk partial  (512 blocks x 256 thr) ----
__global__ __launch_bounds__(256)
void gp_reduce(const float* __restrict__ partial, const float* __restrict__ bias,
               float* __restrict__ out)
{
    int gid = blockIdx.x * 256 + threadIdx.x;  // 131072 float4s
    int ho4 = gid & 31;
    float4 a = *(const float4*)(bias + ho4 * 4);
    #pragma unroll
    for (int ch = 0; ch < NCHUNK; ++ch) {
        float4 v = *(const float4*)(partial + (size_t)ch * 524288 + (size_t)gid * 4);
        a.x += v.x; a.y += v.y; a.z += v.z; a.w += v.w;
    }
    *(float4*)(out + (size_t)gid * 4) = a;
}

extern "C" void kernel_launch(void* const* d_in, const int* in_sizes, int n_in,
                              void* d_out, int out_size, void* d_ws, size_t ws_size,
                              hipStream_t stream)
{
    const float* hid  = (const float*)d_in[0];  // [64,64,128]
    const float* pos  = (const float*)d_in[1];  // [64,64,2]
    const float* W    = (const float*)d_in[2];  // [128,8192]
    const float* bias = (const float*)d_in[3];  // [128]
    float* out = (float*)d_out;

    char* ws = (char*)d_ws;
    __hip_bfloat16* Wb      = (__hip_bfloat16*)(ws);               // 2 MB
    unsigned char*  cellt_g = (unsigned char*) (ws + (2u << 20));  // 256 KB
    float*          partial = (float*)         (ws + (4u << 20));  // 8 MB

    hipLaunchKernelGGL(gp_prep,   dim3(320),  dim3(256), 0, stream, W, pos, Wb, cellt_g);
    hipLaunchKernelGGL(gp_main,   dim3(1024), dim3(256), 0, stream, hid, cellt_g, Wb, partial);
    hipLaunchKernelGGL(gp_reduce, dim3(512),  dim3(256), 0, stream, partial, bias, out);
}

// Round 9
// 48.728 us; speedup vs baseline: 2.5739x; 2.5739x over previous
//
#include <hip/hip_runtime.h>
#include <hip/hip_bf16.h>
#include <stdint.h>

// pooled[b,i,:] = bias + sum_{j!=i} W_cell(b,i,j) . hid[b,j,:]
// R9 = R7 inner loop + XCD-locality. gp_main: 2048 one-wave blocks; block id
// decodes as (xcd = bid&7) -> b = xcd*8 + blocal, so each XCD's L2 only ever
// serves its own 8 batches + the shared 2MB Wb (resident). All per-wave state
// (A-frags, cellt bytes) hoisted; per cell: 8 Wb frag loads (L2-hit), 32 MFMA,
// wave-private LDS transpose, 16 mask-MFMA. No barriers. partial[8] + reduce.

typedef __attribute__((ext_vector_type(8))) short bf16x8;
typedef __attribute__((ext_vector_type(4))) float f32x4;
typedef unsigned int u32;

#define NCHUNK 8   // cell chunks (cq)
#define CPB 8      // cells per chunk

__device__ inline unsigned short bf16bits(float x) {
    __hip_bfloat16 h = __float2bfloat16(x);
    return *reinterpret_cast<unsigned short*>(&h);
}

// ---- prep: 384 blocks x 256 thr ----
//  [0,256):   W -> Wb bf16 [c][hg][ho][e]      (c = bid>>2, ho-quarter = bid&3)
//  [256,320): cell table for b = bid-256
//  [320,384): hid -> Hb bf16 [b][hg][j][e]     (frag-linear, coalesced frags)
__global__ __launch_bounds__(256)
void gp_prep(const float* __restrict__ W, const float* __restrict__ pos,
             const float* __restrict__ hid,
             __hip_bfloat16* __restrict__ Wb,      // [64][16][128][8]
             unsigned char* __restrict__ cellt_g,  // [64][64][64]
             __hip_bfloat16* __restrict__ Hb)      // [64][16][64][8]
{
    const int bid = blockIdx.x, t = threadIdx.x;
    if (bid < 256) {
        __shared__ __attribute__((aligned(16))) __hip_bfloat16 Wl[32][136];
        const int c = bid >> 2, q = bid & 3;
        #pragma unroll
        for (int it = 0; it < 4; ++it) {
            int idx = it * 256 + t;           // 1024 float4s
            int r = idx >> 5, k4 = idx & 31;
            float4 v = *(const float4*)(W + (size_t)(q * 32 + r) * 8192 + c * 128 + k4 * 4);
            __hip_bfloat16* d = &Wl[r][k4 * 4];
            d[0] = __float2bfloat16(v.x); d[1] = __float2bfloat16(v.y);
            d[2] = __float2bfloat16(v.z); d[3] = __float2bfloat16(v.w);
        }
        __syncthreads();
        #pragma unroll
        for (int it = 0; it < 2; ++it) {
            int idx = it * 256 + t;           // 512: hg(16) x hol(32)
            int hg = idx >> 5, hol = idx & 31;
            bf16x8 v = *(const bf16x8*)&Wl[hol][hg * 8];
            *(bf16x8*)(Wb + (size_t)c * 16384 + hg * 1024 + (q * 32 + hol) * 8) = v;
        }
    } else if (bid < 320) {
        __shared__ float ps[128];
        const int b = bid - 256;
        if (t < 128) ps[t] = pos[(size_t)b * 128 + t];
        __syncthreads();
        #pragma unroll
        for (int qq = 0; qq < 16; ++qq) {
            int idx = qq * 256 + t;           // 4096: i x j
            int i = idx >> 6, j = idx & 63;
            float rx = ps[j * 2 + 0] - ps[i * 2 + 0];
            float ry = ps[j * 2 + 1] - ps[i * 2 + 1];
            int gx = (int)((rx + 2.0f) * 2.0f);
            int gy = (int)((ry + 2.0f) * 2.0f);
            gx = gx < 0 ? 0 : (gx > 7 ? 7 : gx);
            gy = gy < 0 ? 0 : (gy > 7 ? 7 : gy);
            cellt_g[(size_t)b * 4096 + idx] =
                (i == j) ? 255 : (unsigned char)(gx * 8 + gy);
        }
    } else {
        const int b = bid - 320;
        #pragma unroll
        for (int q = 0; q < 4; ++q) {
            int idx = q * 256 + t;            // 1024: hg(16) x j(64)
            int hg = idx >> 6, j = idx & 63;
            const float* src = hid + ((size_t)b * 64 + j) * 128 + hg * 8;
            float4 v0 = *(const float4*)src;
            float4 v1 = *(const float4*)(src + 4);
            union { unsigned short us[8]; bf16x8 v; } pk;
            pk.us[0] = bf16bits(v0.x); pk.us[1] = bf16bits(v0.y);
            pk.us[2] = bf16bits(v0.z); pk.us[3] = bf16bits(v0.w);
            pk.us[4] = bf16bits(v1.x); pk.us[5] = bf16bits(v1.y);
            pk.us[6] = bf16bits(v1.z); pk.us[7] = bf16bits(v1.w);
            *(bf16x8*)(Hb + (size_t)b * 8192 + (size_t)idx * 8) = pk.v;
        }
    }
}

// ---- main: 2048 one-wave blocks; bid&7 = XCD -> owns b = (bid&7)*8+blocal ----
__global__ __launch_bounds__(64, 2)
void gp_main(const __hip_bfloat16* __restrict__ Hb,
             const unsigned char* __restrict__ cellt_g,
             const __hip_bfloat16* __restrict__ Wb,
             float* __restrict__ partial)
{
    __shared__ u32 zscr[1024];   // wave-private (1 wave/block), 4KB

    const int beta = blockIdx.x;
    const int xcd = beta & 7;
    const int r = beta >> 3;             // 0..255: blocal(8) x hoq(4) x cq(8)
    const int blocal = r >> 5;
    const int hoq = (r >> 3) & 3;
    const int cq = r & 7;
    const int b = xcd * 8 + blocal;

    const int lane = threadIdx.x;
    const int l15 = lane & 15, kg = lane >> 4;

    // hoisted cellt bytes (i = mt*16+l15, j = ks2*32+kg*8 .. +8)
    uint2 cs[4][2];
    #pragma unroll
    for (int mt = 0; mt < 4; ++mt)
        #pragma unroll
        for (int ks2 = 0; ks2 < 2; ++ks2)
            cs[mt][ks2] = *(const uint2*)(cellt_g + (size_t)b * 4096 +
                                          (mt * 16 + l15) * 64 + ks2 * 32 + kg * 8);

    // hoisted hid A-frags from frag-linear Hb: a[jt][ks], row j=jt*16+l15
    bf16x8 a[4][4];
    #pragma unroll
    for (int jt = 0; jt < 4; ++jt)
        #pragma unroll
        for (int ks = 0; ks < 4; ++ks)
            a[jt][ks] = *(const bf16x8*)(Hb + (size_t)b * 8192 +
                                         ((ks * 4 + kg) * 64 + jt * 16 + l15) * 8);

    f32x4 acc[4][2];
    #pragma unroll
    for (int mt = 0; mt < 4; ++mt) {
        acc[mt][0] = (f32x4){0.f, 0.f, 0.f, 0.f};
        acc[mt][1] = (f32x4){0.f, 0.f, 0.f, 0.f};
    }

    #pragma unroll 2
    for (int cc = 0; cc < CPB; ++cc) {
        const int c = cq * CPB + cc;

        // W B-frags (L2-resident Wb): col ho = hoq*32+fh*16+l15
        bf16x8 wf[4][2];
        #pragma unroll
        for (int ks = 0; ks < 4; ++ks)
            #pragma unroll
            for (int fh = 0; fh < 2; ++fh)
                wf[ks][fh] = *(const bf16x8*)(Wb + (size_t)c * 16384 +
                    ((ks * 4 + kg) * 128 + hoq * 32 + fh * 16 + l15) * 8);

        // stage-1: z[jt][fh] = hid(j x h) @ W_c^T(h x ho), 32 MFMA
        f32x4 z[4][2];
        #pragma unroll
        for (int jt = 0; jt < 4; ++jt) {
            z[jt][0] = (f32x4){0.f, 0.f, 0.f, 0.f};
            z[jt][1] = (f32x4){0.f, 0.f, 0.f, 0.f};
        }
        #pragma unroll
        for (int ks = 0; ks < 4; ++ks)
            #pragma unroll
            for (int jt = 0; jt < 4; ++jt) {
                z[jt][0] = __builtin_amdgcn_mfma_f32_16x16x32_bf16(a[jt][ks], wf[ks][0], z[jt][0], 0, 0, 0);
                z[jt][1] = __builtin_amdgcn_mfma_f32_16x16x32_bf16(a[jt][ks], wf[ks][1], z[jt][1], 0, 0, 0);
            }

        // pack z -> zscr; jp=j/2; addr32=(jp*32+hol)^(((jp>>2)&3)<<3)  [R6/R7-verified]
        #pragma unroll
        for (int jt = 0; jt < 4; ++jt)
            #pragma unroll
            for (int fh = 0; fh < 2; ++fh) {
                u32 p0 = (u32)bf16bits(z[jt][fh][0]) | ((u32)bf16bits(z[jt][fh][1]) << 16);
                u32 p1 = (u32)bf16bits(z[jt][fh][2]) | ((u32)bf16bits(z[jt][fh][3]) << 16);
                int X = ((jt * 2 + (kg >> 1)) & 3) << 3;
                int a32 = (((jt * 8 + kg * 2) * 32) + fh * 16 + l15) ^ X;
                zscr[a32] = p0;
                zscr[a32 + 32] = p1;
            }

        // transpose read: b2[ks2][fh], k=j=ks2*32+kg*8+e   [R6/R7-verified]
        bf16x8 b2[2][2];
        #pragma unroll
        for (int ks2 = 0; ks2 < 2; ++ks2)
            #pragma unroll
            for (int fh = 0; fh < 2; ++fh) {
                int base = (((ks2 * 16 + kg * 4) * 32) + fh * 16 + l15) ^ (kg << 3);
                union { u32 wd[4]; bf16x8 v; } rr;
                rr.wd[0] = zscr[base];
                rr.wd[1] = zscr[base + 32];
                rr.wd[2] = zscr[base + 64];
                rr.wd[3] = zscr[base + 96];
                b2[ks2][fh] = rr.v;
            }

        // stage-2: acc(i,ho) += mask(i x j) @ z(j x ho); mask from hoisted cs
        #pragma unroll
        for (int mt = 0; mt < 4; ++mt) {
            #pragma unroll
            for (int ks2 = 0; ks2 < 2; ++ks2) {
                union { u32 wd[4]; bf16x8 v; } m;
                u32 s0 = cs[mt][ks2].x, s1 = cs[mt][ks2].y;
                #pragma unroll
                for (int k = 0; k < 4; ++k) {
                    u32 s = (k < 2) ? s0 : s1;
                    u32 b0 = (s >> ((k & 1) * 16)) & 0xFFu;
                    u32 b1 = (s >> ((k & 1) * 16 + 8)) & 0xFFu;
                    m.wd[k] = (b0 == (u32)c ? 0x3F80u : 0u) | (b1 == (u32)c ? 0x3F800000u : 0u);
                }
                acc[mt][0] = __builtin_amdgcn_mfma_f32_16x16x32_bf16(m.v, b2[ks2][0], acc[mt][0], 0, 0, 0);
                acc[mt][1] = __builtin_amdgcn_mfma_f32_16x16x32_bf16(m.v, b2[ks2][1], acc[mt][1], 0, 0, 0);
            }
        }
    }

    // epilogue: partial[cq][b][i][hoq*32..]
    float* pb = partial + (((size_t)cq * 64 + b) * 64) * 128 + hoq * 32;
    #pragma unroll
    for (int mt = 0; mt < 4; ++mt)
        #pragma unroll
        for (int fh = 0; fh < 2; ++fh)
            #pragma unroll
            for (int r4 = 0; r4 < 4; ++r4) {
                int i = mt * 16 + kg * 4 + r4;
                pb[(size_t)i * 128 + fh * 16 + l15] = acc[mt][fh][r4];
            }
}

// ---- reduce: out = bias + sum_cq partial  (512 blocks x 256 thr) ----
__global__ __launch_bounds__(256)
void gp_reduce(const float* __restrict__ partial, const float* __restrict__ bias,
               float* __restrict__ out)
{
    int gid = blockIdx.x * 256 + threadIdx.x;  // 131072 float4s
    int ho4 = gid & 31;
    float4 a = *(const float4*)(bias + ho4 * 4);
    #pragma unroll
    for (int ch = 0; ch < NCHUNK; ++ch) {
        float4 v = *(const float4*)(partial + (size_t)ch * 524288 + (size_t)gid * 4);
        a.x += v.x; a.y += v.y; a.z += v.z; a.w += v.w;
    }
    *(float4*)(out + (size_t)gid * 4) = a;
}

extern "C" void kernel_launch(void* const* d_in, const int* in_sizes, int n_in,
                              void* d_out, int out_size, void* d_ws, size_t ws_size,
                              hipStream_t stream)
{
    const float* hid  = (const float*)d_in[0];  // [64,64,128]
    const float* pos  = (const float*)d_in[1];  // [64,64,2]
    const float* W    = (const float*)d_in[2];  // [128,8192]
    const float* bias = (const float*)d_in[3];  // [128]
    float* out = (float*)d_out;

    char* ws = (char*)d_ws;
    __hip_bfloat16* Wb      = (__hip_bfloat16*)(ws);               // 2 MB
    __hip_bfloat16* Hb      = (__hip_bfloat16*)(ws + (2u << 20));  // 1 MB
    unsigned char*  cellt_g = (unsigned char*) (ws + (3u << 20));  // 256 KB
    float*          partial = (float*)         (ws + (4u << 20));  // 16 MB

    hipLaunchKernelGGL(gp_prep,   dim3(384),  dim3(256), 0, stream,
                       W, pos, hid, Wb, cellt_g, Hb);
    hipLaunchKernelGGL(gp_main,   dim3(2048), dim3(64),  0, stream,
                       Hb, cellt_g, Wb, partial);
    hipLaunchKernelGGL(gp_reduce, dim3(512),  dim3(256), 0, stream,
                       partial, bias, out);
}